// Round 13
// baseline (190.822 us; speedup 1.0000x reference)
//
#include <hip/hip_runtime.h>
#include <cstdint>
#include <cstddef>

#define NB 128      // N
#define KPP 32      // Kp
#define VV 2048     // V
#define SS 200      // S (tm1)
#define WID 32      // width == K
#define NEXT_BASE (KPP*VV)     // 65536
#define KBLK 16                // blocks per n (each block = 4 waves = 2 rows x 2 halves)
#define CAPW 128               // per-wave survivor cap
#define NWAVE (KPP*2)          // 64 wave-lists per n
#define NLIST (NWAVE*WID + WID) // 2080 merge candidates
#define FCAP 256               // merge filtered-list cap (overflow -> full exact rank)

// output layout (flat f32, concat in return order)
#define SZ_YNEXT ((size_t)(SS+1)*NB*WID)               // 823296
#define NK       ((size_t)NB*WID)                      // 4096
#define O_LAST   (SZ_YNEXT)
#define O_LENS   (SZ_YNEXT + NK)
#define O_NB     (SZ_YNEXT + 2*NK)
#define O_B      (SZ_YNEXT + 3*NK)
#define O_PREF   (SZ_YNEXT + 4*NK)                     // size NB*WID*WID
#define O_SRC    (SZ_YNEXT + 4*NK + (size_t)NB*WID*WID)
#define O_NOEXT  (SZ_YNEXT + 5*NK + (size_t)NB*WID*WID)
#define SZ_PREF  ((size_t)NB*WID*WID)                  // 131072

__device__ __forceinline__ unsigned fkey(float f) {
    unsigned u = __float_as_uint(f);
    return (u & 0x80000000u) ? ~u : (u | 0x80000000u);
}
__device__ __forceinline__ float funkey(unsigned k) {
    unsigned u = (k & 0x80000000u) ? (k & 0x7FFFFFFFu) : ~k;
    return __uint_as_float(u);
}
__device__ __forceinline__ unsigned long long shflx64(unsigned long long v, int m) {
    int lo = __shfl_xor((int)(unsigned)v, m);
    int hi = __shfl_xor((int)(unsigned)(v >> 32), m);
    return ((unsigned long long)(unsigned)hi << 32) | (unsigned)lo;
}

// LDS arena (overlaid across phases): 4672 u32 = 18688 B
//  slice phase : hm[4][64] @0..255 | bk[4][128] @256..767 | bi[4][128] @768..1279
//  merge absorb: abL[32][32] @0..1023            (slice data dead by then)
//  merge stage : cf[2080] @0..2079 | ci[2080] @2080..4159 | ff[256] @4160 | fi[256] @4416
#define SMEM_WORDS 4672

__global__ __launch_bounds__(256) void fused_kernel(
    const float* __restrict__ ext,     // [N][Kp][V]
    const float* __restrict__ nonext,  // [N][V]
    const float* __restrict__ blank,   // [N]
    const float* __restrict__ nbp_g,   // [N][Kp]
    const float* __restrict__ bp_g,    // [N][Kp]
    const int*   __restrict__ yprev,   // [S][N][Kp]
    const int*   __restrict__ ylast,   // [N][Kp]
    const int*   __restrict__ ylens,   // [N][Kp]
    const int*   __restrict__ pip,     // [N][Kp][Kp]
    unsigned* __restrict__ wsF, int* __restrict__ wsI, float* __restrict__ wsAb,
    int* __restrict__ wsCnt,
    float* __restrict__ out)
{
    const int blk  = blockIdx.x;
    const int n    = blk >> 4;          // KBLK = 16
    const int kb   = blk & 15;
    const int tid  = threadIdx.x;
    const int w    = tid >> 6;          // 4 waves
    const int lane = tid & 63;
    const int k    = kb*2 + (w >> 1);
    const int half = w & 1;
    const int g    = ((n*KPP + k) << 1) + half;   // this wave's ws list id

    __shared__ unsigned s_mem[SMEM_WORDS];
    __shared__ int      s_ticket;
    __shared__ int      s_last[KPP];
    __shared__ float    s_bne[KPP], s_nbne[KPP];
    __shared__ unsigned long long s_tau;
    __shared__ int      s_cnt;
    __shared__ int      s_selidx[WID];
    __shared__ float    s_selval[WID];

    unsigned (*s_hm)[VV/32] = (unsigned(*)[VV/32])s_mem;     // [4][64]
    unsigned (*s_bk)[CAPW]  = (unsigned(*)[CAPW])(s_mem + 256);
    int      (*s_bi)[CAPW]  = (int(*)[CAPW])(s_mem + 768);

    // ================= slice phase (round-11 proven) =================
    s_hm[w][lane] = 0u;                 // wave-private, no barrier needed

    const int   tlen = ylens[n*KPP + k];
    int last = ylast[n*KPP + k]; last = min(max(last, 0), VV-1);
    const float nbp = nbp_g[n*KPP + k];
    const float bp  = bp_g[n*KPP + k];

    const float4* g4 = (const float4*)(ext + ((size_t)n*KPP + k)*VV + half*1024);
    float4 f[4];
    #pragma unroll
    for (int j = 0; j < 4; ++j) f[j] = g4[lane + 64*j];

    if (lane < KPP) {
        int j = lane;
        int tcl = min(max(tlen, 0), SS-1);
        int tm  = yprev[((size_t)tcl*NB + n)*KPP + j];
        tm = min(max(tm, 0), VV-1);
        bool ex = (tlen + 1 == ylens[n*KPP + j]) && (pip[((size_t)n*KPP + k)*KPP + j] != 0);
        if (ex) atomicOr(&s_hm[w][tm >> 5], 1u << (tm & 31));
        if (half == 0) {
            float ev = ex ? ext[((size_t)n*KPP + k)*VV + tm] : 0.0f;
            float bb = (tm == last) ? 0.0f : nbp;
            wsAb[((size_t)n*KPP + k)*KPP + j] = ex ? (bb + bp)*ev : 0.0f;
        }
    }

    unsigned key[16];
    #pragma unroll
    for (int j = 0; j < 4; ++j) {
        const float fe[4] = {f[j].x, f[j].y, f[j].z, f[j].w};
        #pragma unroll
        for (int e = 0; e < 4; ++e) {
            int vl = 4*lane + 256*j + e;
            int v  = (half << 10) + vl;
            float base = (v == last) ? 0.0f : nbp;
            float val  = (base + bp) * fe[e];
            if ((s_hm[w][v >> 5] >> (v & 31)) & 1u) val = -INFINITY;
            key[j*4 + e] = fkey(val);
        }
    }

    unsigned m = key[0];
    #pragma unroll
    for (int i = 1; i < 16; ++i) m = max(m, key[i]);
    const unsigned m16 = m >> 16;

    unsigned tau16 = 0;
    {
        int need = 32;
        #pragma unroll
        for (int b = 15; b >= 0; --b) {
            unsigned pb1 = (tau16 >> b) | 1u;
            unsigned long long msk = __ballot((m16 >> b) == pb1);
            int cnt = __popcll(msk);
            if (cnt >= need) tau16 |= (1u << b);
            else             need -= cnt;
        }
    }

    const unsigned long long lmask = (1ull << lane) - 1ull;
    int off2 = 0;
    #pragma unroll
    for (int i = 0; i < 16; ++i) {
        bool sel = (key[i] >> 16) >= tau16;
        unsigned long long msk = __ballot(sel);
        if (sel) {
            int slot = off2 + __popcll(msk & lmask);
            if (slot < CAPW) {
                s_bk[w][slot] = key[i];
                s_bi[w][slot] = (k << 11) + (half << 10) + (4*lane + 256*(i >> 2) + (i & 3));
            }
        }
        off2 += __popcll(msk);
    }
    int total = off2;

    if (total > CAPW) {
        int need = WID;
        unsigned T = 0, istar = 0;
        for (int b = 31; b >= 0; --b) {
            unsigned pb1 = (T >> b) | 1u;
            int c1 = 0;
            #pragma unroll
            for (int i = 0; i < 16; ++i) c1 += ((key[i] >> b) == pb1) ? 1 : 0;
            #pragma unroll
            for (int off = 32; off; off >>= 1) c1 += __shfl_xor(c1, off);
            if (c1 >= need) T |= (1u << b);
            else need -= c1;
        }
        for (int b = 9; b >= 0; --b) {
            int c0 = 0;
            #pragma unroll
            for (int i = 0; i < 16; ++i) {
                unsigned vv = (unsigned)(4*lane + 256*(i >> 2) + (i & 3));
                if (key[i] == T && (vv >> (b+1)) == (istar >> (b+1)) && !((vv >> b) & 1u)) c0++;
            }
            #pragma unroll
            for (int off = 32; off; off >>= 1) c0 += __shfl_xor(c0, off);
            if (c0 >= need) { } else { need -= c0; istar |= (1u << b); }
        }
        int o2 = 0;
        #pragma unroll
        for (int i = 0; i < 16; ++i) {
            unsigned vv = (unsigned)(4*lane + 256*(i >> 2) + (i & 3));
            bool sel = (key[i] > T || (key[i] == T && vv <= istar));
            unsigned long long msk = __ballot(sel);
            if (sel) {
                int slot = o2 + __popcll(msk & lmask);
                s_bk[w][slot] = key[i];
                s_bi[w][slot] = (k << 11) + (half << 10) + (int)vv;
            }
            o2 += __popcll(msk);
        }
        total = WID;
    }

    // in-wave rank-sort (~44); write this wave's sorted top-32 to ws
    for (int e = lane; e < total; e += 64) {
        unsigned mf = s_bk[w][e]; int mi = s_bi[w][e];
        int rank = 0;
        for (int j2 = 0; j2 < total; ++j2) {
            unsigned fq = s_bk[w][j2];
            rank += (fq > mf || (fq == mf && s_bi[w][j2] < mi)) ? 1 : 0;
        }
        if (rank < WID) { wsF[g*WID + rank] = mf; wsI[g*WID + rank] = mi; }
    }

    // ================= ticket: last block of this n merges =================
    __threadfence();            // release our global writes to device scope
    __syncthreads();            // all waves of this block done
    if (tid == 0) s_ticket = atomicAdd(&wsCnt[n], 1);
    __syncthreads();
    if (s_ticket != KBLK-1) return;
    __threadfence();            // acquire: invalidate stale cached lines

    // ================= merge tail (round-11 proven, n fixed) =================
    float    (*s_abL)[KPP] = (float(*)[KPP])s_mem;       // overlays slice region
    unsigned *s_cf = s_mem;                              // [2080] (after absorb done)
    int      *s_ci = (int*)(s_mem + 2080);
    unsigned *s_ff = s_mem + 4160;
    int      *s_fi = (int*)(s_mem + 4416);

    if (tid == 0) s_cnt = 0;
    if (tid < KPP) {
        int kq = tid;
        int lst = ylast[n*KPP + kq]; lst = min(max(lst, 0), VV-1);
        float a = nbp_g[n*KPP + kq], b = bp_g[n*KPP + kq];
        s_last[kq] = lst;
        s_bne[kq]  = (a + b) * blank[n];
        s_nbne[kq] = a * nonext[(size_t)n*VV + lst];
    }
    __syncthreads();            // slice LDS dead; safe to overlay
    for (int i = tid; i < KPP*KPP; i += 256)
        s_abL[i >> 5][i & 31] = wsAb[(size_t)n*KPP*KPP + i];
    __syncthreads();
    if (tid < KPP) {            // absorb: serial k-order sum (bit-exact)
        int j = tid;
        float acc = s_nbne[j];
        #pragma unroll
        for (int kq = 0; kq < KPP; ++kq) acc += s_abL[kq][j];
        s_nbne[j] = acc;
    }
    __syncthreads();            // abL dead; cf/ci overlay safe

    for (int i = tid; i < NLIST; i += 256) {
        if (i < NWAVE*WID) {
            s_cf[i] = wsF[(size_t)n*NWAVE*WID + i];
            s_ci[i] = wsI[(size_t)n*NWAVE*WID + i];
        } else {
            int j = i - NWAVE*WID;
            s_cf[i] = fkey(s_nbne[j] + s_bne[j]);
            s_ci[i] = NEXT_BASE + j;
        }
    }
    __syncthreads();

    if (tid < 64) {             // tau = max over waves of their 32nd packed key
        int i = tid*WID + (WID-1);
        unsigned long long p = ((unsigned long long)s_cf[i] << 32) | (unsigned)(~s_ci[i]);
        #pragma unroll
        for (int off = 32; off; off >>= 1) {
            unsigned long long o = shflx64(p, off);
            if (o > p) p = o;
        }
        if (tid == 0) s_tau = p;
    }
    __syncthreads();
    const unsigned long long tau = s_tau;

    for (int i = tid; i < NLIST; i += 256) {
        unsigned long long p = ((unsigned long long)s_cf[i] << 32) | (unsigned)(~s_ci[i]);
        if (p >= tau) {
            int slot = atomicAdd(&s_cnt, 1);
            if (slot < FCAP) { s_ff[slot] = s_cf[i]; s_fi[slot] = s_ci[i]; }
        }
    }
    __syncthreads();
    const int fcnt = s_cnt;

    if (fcnt <= FCAP) {
        for (int e = tid; e < fcnt; e += 256) {
            unsigned mf = s_ff[e]; int mi = s_fi[e];
            int rank = 0;
            for (int j = 0; j < fcnt; ++j) {
                unsigned fq = s_ff[j];
                rank += (fq > mf || (fq == mf && s_fi[j] < mi)) ? 1 : 0;
            }
            if (rank < WID) { s_selidx[rank] = mi; s_selval[rank] = funkey(mf); }
        }
    } else {
        for (int e = tid; e < NLIST; e += 256) {   // overflow: exact full rank
            unsigned mf = s_cf[e]; int mi = s_ci[e];
            int rank = 0;
            for (int j = 0; j < NLIST; ++j) {
                unsigned fq = s_cf[j];
                rank += (fq > mf || (fq == mf && s_ci[j] < mi)) ? 1 : 0;
            }
            if (rank < WID) { s_selidx[rank] = mi; s_selval[rank] = funkey(mf); }
        }
    }
    __syncthreads();

    if (tid < WID) {            // per-k scalar outputs
        int kq = tid;
        int ind = s_selidx[kq];
        bool noext = ind >= NEXT_BASE;
        int src  = noext ? (ind - NEXT_BASE) : (ind >> 11);
        int extk = ind & (VV-1);
        int plen = ylens[n*KPP + src];
        int lens = plen + (noext ? 0 : 1);
        float nbv = noext ? s_nbne[src] : s_selval[kq];
        float bv  = noext ? s_bne[src]  : 0.0f;
        int lastv = noext ? s_last[src] : extk;
        size_t o = (size_t)n*WID + kq;
        out[O_LAST  + o] = (float)lastv;
        out[O_LENS  + o] = (float)lens;
        out[O_NB    + o] = nbv;
        out[O_B     + o] = bv;
        out[O_SRC   + o] = (float)src;
        out[O_NOEXT + o] = noext ? 1.0f : 0.0f;
    }
}

// ---------------- fused y_next + next_is_prefix (full-chip; round-11 proven) ----------------
__global__ void epilogue_kernel(const int* __restrict__ yprev, const int* __restrict__ pip,
                                float* __restrict__ out) {
    int id = blockIdx.x*blockDim.x + threadIdx.x;
    if (id < (int)SZ_YNEXT) {
        int k = id & 31;
        int n = (id >> 5) & 127;
        int t = id >> 12;                    // NB*WID = 4096 = 2^12
        size_t o = (size_t)n*WID + k;
        int src    = (int)out[O_SRC + o];
        bool noext = out[O_NOEXT + o] != 0.0f;
        int lens   = (int)out[O_LENS + o];
        int plen   = lens - (noext ? 0 : 1);
        int extk   = noext ? src : (int)out[O_LAST + o];
        float val;
        if (t == plen)      val = (float)extk;
        else if (t < SS)    val = (float)yprev[((size_t)t*NB + n)*KPP + src];
        else                val = 0.0f;
        out[id] = val;
    } else if (id < (int)(SZ_YNEXT + SZ_PREF)) {
        int pid = id - (int)SZ_YNEXT;
        int j = pid & 31;
        int k = (pid >> 5) & 31;
        int n = pid >> 10;
        size_t ok = (size_t)n*WID + k, oj = (size_t)n*WID + j;
        int  src_k = (int)out[O_SRC + ok];
        int  src_j = (int)out[O_SRC + oj];
        bool no_k  = out[O_NOEXT + ok] != 0.0f;
        bool no_j  = out[O_NOEXT + oj] != 0.0f;
        int  lens_k = (int)out[O_LENS + ok];
        int  lens_j = (int)out[O_LENS + oj];
        int  ext_k = no_k ? src_k : (int)out[O_LAST + ok];
        int  ext_j = no_j ? src_j : (int)out[O_LAST + oj];
        int  plen_j = lens_j - (no_j ? 0 : 1);
        bool prefix = pip[((size_t)n*KPP + src_k)*KPP + src_j] != 0;
        bool leq    = lens_k <= lens_j;
        int  tstar  = max(lens_k - 1, 0);
        int  tmj;
        if (tstar == plen_j)   tmj = ext_j;
        else if (tstar < SS)   tmj = yprev[((size_t)tstar*NB + n)*KPP + src_j];
        else                   tmj = 0;
        bool matches = (tmj == ext_k);
        bool res = prefix && leq && (no_k || matches);
        out[O_PREF + (size_t)n*WID*WID + (size_t)k*WID + j] = res ? 1.0f : 0.0f;
    }
}

extern "C" void kernel_launch(void* const* d_in, const int* in_sizes, int n_in,
                              void* d_out, int out_size, void* d_ws, size_t ws_size,
                              hipStream_t stream) {
    const float* ext    = (const float*)d_in[0];
    const float* nonext = (const float*)d_in[1];
    const float* blank  = (const float*)d_in[2];
    const float* nbp    = (const float*)d_in[3];
    const float* bp     = (const float*)d_in[4];
    const int*   yprev  = (const int*)d_in[5];
    const int*   ylast  = (const int*)d_in[6];
    const int*   ylens  = (const int*)d_in[7];
    const int*   pip    = (const int*)d_in[8];
    float* out = (float*)d_out;

    unsigned* wsF  = (unsigned*)d_ws;                      // NB*64*32 u32 (1 MB)
    int*      wsI  = (int*)d_ws + (size_t)NB*NWAVE*WID;    // +1 MB
    float*    wsAb = (float*)d_ws + 2*(size_t)NB*NWAVE*WID;// NB*32*32 f32 (512 KB)
    int*      wsCnt= (int*)((float*)wsAb + (size_t)NB*KPP*KPP);  // NB ints

    hipMemsetAsync(wsCnt, 0, NB*sizeof(int), stream);
    fused_kernel<<<NB*KBLK, 256, 0, stream>>>(ext, nonext, blank, nbp, bp, yprev,
                                              ylast, ylens, pip, wsF, wsI, wsAb,
                                              wsCnt, out);
    int tot = (int)(SZ_YNEXT + SZ_PREF);
    epilogue_kernel<<<(tot + 255)/256, 256, 0, stream>>>(yprev, pip, out);
}

// Round 14
// 32.028 us; speedup vs baseline: 5.9580x; 5.9580x over previous
//
#include <hip/hip_runtime.h>
#include <cstdint>
#include <cstddef>

#define NB 128      // N
#define KPP 32      // Kp
#define VV 2048     // V
#define SS 200      // S (tm1)
#define WID 32      // width == K
#define NEXT_BASE (KPP*VV)     // 65536
#define KBLK 16                // blocks per n (each block = 4 waves = 2 rows x 2 halves)
#define CAPW 128               // per-wave survivor cap
#define NWAVE (KPP*2)          // 64 wave-lists per n
#define NLIST (NWAVE*WID + WID) // 2080 merge candidates
#define FCAP 256               // merge filtered-list cap (overflow -> full exact rank)

// output layout (flat f32, concat in return order)
#define SZ_YNEXT ((size_t)(SS+1)*NB*WID)               // 823296
#define NK       ((size_t)NB*WID)                      // 4096
#define O_LAST   (SZ_YNEXT)
#define O_LENS   (SZ_YNEXT + NK)
#define O_NB     (SZ_YNEXT + 2*NK)
#define O_B      (SZ_YNEXT + 3*NK)
#define O_PREF   (SZ_YNEXT + 4*NK)                     // size NB*WID*WID
#define O_SRC    (SZ_YNEXT + 4*NK + (size_t)NB*WID*WID)
#define O_NOEXT  (SZ_YNEXT + 5*NK + (size_t)NB*WID*WID)
#define SZ_PREF  ((size_t)NB*WID*WID)                  // 131072

typedef unsigned long long u64;

__device__ __forceinline__ unsigned fkey(float f) {
    unsigned u = __float_as_uint(f);
    return (u & 0x80000000u) ? ~u : (u | 0x80000000u);
}
__device__ __forceinline__ float funkey(unsigned k) {
    unsigned u = (k & 0x80000000u) ? (k & 0x7FFFFFFFu) : ~k;
    return __uint_as_float(u);
}
__device__ __forceinline__ u64 pack(unsigned key, unsigned idx) {
    return ((u64)key << 32) | (unsigned)(~idx);        // desc value, asc idx
}
__device__ __forceinline__ u64 shflx64(u64 v, int m) {
    int lo = __shfl_xor((int)(unsigned)v, m);
    int hi = __shfl_xor((int)(unsigned)(v >> 32), m);
    return ((u64)(unsigned)hi << 32) | (unsigned)lo;
}

// ---------------- kernel A: one wave per HALF k-row, wave-autonomous (round-11 proven) ----------------
__global__ __launch_bounds__(256) void slice_topk_kernel(
    const float* __restrict__ ext,     // [N][Kp][V]
    const float* __restrict__ nbp_g,   // [N][Kp]
    const float* __restrict__ bp_g,    // [N][Kp]
    const int*   __restrict__ yprev,   // [S][N][Kp]
    const int*   __restrict__ ylast,   // [N][Kp]
    const int*   __restrict__ ylens,   // [N][Kp]
    const int*   __restrict__ pip,     // [N][Kp][Kp]
    u64* __restrict__ wsP, float* __restrict__ wsAb)
{
    const int blk  = blockIdx.x;
    const int n    = blk >> 4;          // KBLK = 16
    const int kb   = blk & 15;
    const int tid  = threadIdx.x;
    const int w    = tid >> 6;          // 4 waves
    const int lane = tid & 63;
    const int k    = kb*2 + (w >> 1);
    const int half = w & 1;
    const int g    = ((n*KPP + k) << 1) + half;   // this wave's ws list id

    __shared__ unsigned s_hm[4][VV/32];     // wave-private hm (full row), 1 KB
    __shared__ u64      s_bp64[4][CAPW];    // wave-private packed survivor buffers, 4 KB

    s_hm[w][lane] = 0u;                 // VV/32 == 64 == lane count (wave-private)

    // per-row params (wave-uniform addresses -> broadcast loads)
    const int   tlen = ylens[n*KPP + k];
    int last = ylast[n*KPP + k]; last = min(max(last, 0), VV-1);
    const float nbp = nbp_g[n*KPP + k];
    const float bp  = bp_g[n*KPP + k];

    // issue the 4 float4 loads early (16 floats/lane, registers only)
    const float4* g4 = (const float4*)(ext + ((size_t)n*KPP + k)*VV + half*1024);
    float4 f[4];
    #pragma unroll
    for (int j = 0; j < 4; ++j) f[j] = g4[lane + 64*j];

    // has-match bits + absorb terms (same-wave LDS ordering; no barrier needed)
    if (lane < KPP) {
        int j = lane;
        int tcl = min(max(tlen, 0), SS-1);
        int tm  = yprev[((size_t)tcl*NB + n)*KPP + j];
        tm = min(max(tm, 0), VV-1);
        bool ex = (tlen + 1 == ylens[n*KPP + j]) && (pip[((size_t)n*KPP + k)*KPP + j] != 0);
        if (ex) atomicOr(&s_hm[w][tm >> 5], 1u << (tm & 31));
        if (half == 0) {
            float ev = ex ? ext[((size_t)n*KPP + k)*VV + tm] : 0.0f;
            float bb = (tm == last) ? 0.0f : nbp;
            wsAb[((size_t)n*KPP + k)*KPP + j] = ex ? (bb + bp)*ev : 0.0f;
        }
    }

    // 16 keys in registers; v_local = 4*lane + 256*j + e in [0,1024)
    unsigned key[16];
    #pragma unroll
    for (int j = 0; j < 4; ++j) {
        const float fe[4] = {f[j].x, f[j].y, f[j].z, f[j].w};
        #pragma unroll
        for (int e = 0; e < 4; ++e) {
            int vl = 4*lane + 256*j + e;
            int v  = (half << 10) + vl;
            float base = (v == last) ? 0.0f : nbp;
            float val  = (base + bp) * fe[e];
            if ((s_hm[w][v >> 5] >> (v & 31)) & 1u) val = -INFINITY;
            key[j*4 + e] = fkey(val);
        }
    }

    // lane max (top 16 bits suffice for the threshold)
    unsigned m = key[0];
    #pragma unroll
    for (int i = 1; i < 16; ++i) m = max(m, key[i]);
    const unsigned m16 = m >> 16;

    // tau16 = EXACT 32nd-largest of the 64 (lane-max >> 16) values: 16 ballot steps
    unsigned tau16 = 0;
    {
        int need = 32;
        #pragma unroll
        for (int b = 15; b >= 0; --b) {
            unsigned pb1 = (tau16 >> b) | 1u;
            unsigned long long msk = __ballot((m16 >> b) == pb1);
            int cnt = __popcll(msk);
            if (cnt >= need) tau16 |= (1u << b);
            else             need -= cnt;
        }
    }
    // guarantee: >=32 lanes have (m>>16) >= tau16  =>  >=32 keys with (key>>16) >= tau16

    // optimistic gather into wave-private LDS (packed); count via ballot prefix
    const unsigned long long lmask = (1ull << lane) - 1ull;
    int off2 = 0;
    #pragma unroll
    for (int i = 0; i < 16; ++i) {
        bool sel = (key[i] >> 16) >= tau16;
        unsigned long long msk = __ballot(sel);
        if (sel) {
            int slot = off2 + __popcll(msk & lmask);
            if (slot < CAPW) {
                unsigned gidx = (unsigned)((k << 11) + (half << 10) + (4*lane + 256*(i >> 2) + (i & 3)));
                s_bp64[w][slot] = pack(key[i], gidx);
            }
        }
        off2 += __popcll(msk);
    }
    int total = off2;

    if (total > CAPW) {
        // exact fallback: key-bit radix, then idx radix among ties (shuffle-only)
        int need = WID;
        unsigned T = 0, istar = 0;
        for (int b = 31; b >= 0; --b) {
            unsigned pb1 = (T >> b) | 1u;
            int c1 = 0;
            #pragma unroll
            for (int i = 0; i < 16; ++i) c1 += ((key[i] >> b) == pb1) ? 1 : 0;
            #pragma unroll
            for (int off = 32; off; off >>= 1) c1 += __shfl_xor(c1, off);
            if (c1 >= need) T |= (1u << b);
            else need -= c1;
        }
        for (int b = 9; b >= 0; --b) {          // v_local < 1024 -> 10 bits
            int c0 = 0;
            #pragma unroll
            for (int i = 0; i < 16; ++i) {
                unsigned vv = (unsigned)(4*lane + 256*(i >> 2) + (i & 3));
                if (key[i] == T && (vv >> (b+1)) == (istar >> (b+1)) && !((vv >> b) & 1u)) c0++;
            }
            #pragma unroll
            for (int off = 32; off; off >>= 1) c0 += __shfl_xor(c0, off);
            if (c0 >= need) { } else { need -= c0; istar |= (1u << b); }
        }
        int o2 = 0;
        #pragma unroll
        for (int i = 0; i < 16; ++i) {
            unsigned vv = (unsigned)(4*lane + 256*(i >> 2) + (i & 3));
            bool sel = (key[i] > T || (key[i] == T && vv <= istar));
            unsigned long long msk = __ballot(sel);
            if (sel) {
                int slot = o2 + __popcll(msk & lmask);
                unsigned gidx = (unsigned)((k << 11) + (half << 10) + (int)vv);
                s_bp64[w][slot] = pack(key[i], gidx);
            }
            o2 += __popcll(msk);
        }
        total = WID;    // exactly 32 selected
    }

    // in-wave rank-sort (~44 elements, single b64 read + u64 cmp per pair);
    // write this wave's sorted top-32 packed to ws (one 8B store per rank)
    for (int e = lane; e < total; e += 64) {
        u64 pe = s_bp64[w][e];
        int rank = 0;
        for (int j2 = 0; j2 < total; ++j2)
            rank += (s_bp64[w][j2] > pe) ? 1 : 0;
        if (rank < WID) wsP[(size_t)g*WID + rank] = pe;
    }
}

// ---------------- kernel B: merge (packed tau-filter) + epilogue scalars ----------------
__global__ __launch_bounds__(256) void merge_kernel(
    const float* __restrict__ nonext,
    const float* __restrict__ blank,
    const float* __restrict__ nbp_g,
    const float* __restrict__ bp_g,
    const int*   __restrict__ ylast,
    const int*   __restrict__ ylens,
    const u64* __restrict__ wsP, const float* __restrict__ wsAb,
    float* __restrict__ out)
{
    const int n   = blockIdx.x;
    const int tid = threadIdx.x;

    __shared__ int      s_last[KPP];
    __shared__ float    s_bne[KPP], s_nbne[KPP];
    __shared__ float    s_abL[KPP][KPP];
    __shared__ u64      s_cp[NLIST];       // packed candidates, 16.6 KB
    __shared__ u64      s_fp[FCAP];
    __shared__ u64      s_tau;
    __shared__ int      s_cnt;
    __shared__ int      s_selidx[WID];
    __shared__ float    s_selval[WID];

    if (tid == 0) s_cnt = 0;
    if (tid < KPP) {
        int k = tid;
        int last = ylast[n*KPP + k]; last = min(max(last, 0), VV-1);
        float a = nbp_g[n*KPP + k], b = bp_g[n*KPP + k];
        s_last[k] = last;
        s_bne[k]  = (a + b) * blank[n];
        s_nbne[k] = a * nonext[(size_t)n*VV + last];
    }
    for (int i = tid; i < KPP*KPP; i += 256)
        s_abL[i >> 5][i & 31] = wsAb[(size_t)n*KPP*KPP + i];
    __syncthreads();
    if (tid < KPP) {    // absorb: serial k-order sum (bit-exact; zero terms neutral)
        int j = tid;
        float acc = s_nbne[j];
        #pragma unroll
        for (int k = 0; k < KPP; ++k) acc += s_abL[k][j];
        s_nbne[j] = acc;
    }
    __syncthreads();

    // candidate list: 64 wave-top-32s (packed, coalesced 8B loads) + 32 nonext
    for (int i = tid; i < NLIST; i += 256) {
        if (i < NWAVE*WID) {
            s_cp[i] = wsP[(size_t)n*NWAVE*WID + i];
        } else {
            int j = i - NWAVE*WID;
            s_cp[i] = pack(fkey(s_nbne[j] + s_bne[j]), (unsigned)(NEXT_BASE + j));
        }
    }
    __syncthreads();

    // tau = max over waves of their 32nd packed key (lower bound on global 32nd)
    if (tid < 64) {
        u64 p = s_cp[tid*WID + (WID-1)];
        #pragma unroll
        for (int off = 32; off; off >>= 1) {
            u64 o = shflx64(p, off);
            if (o > p) p = o;
        }
        if (tid == 0) s_tau = p;
    }
    __syncthreads();
    const u64 tau = s_tau;

    for (int i = tid; i < NLIST; i += 256) {
        u64 p = s_cp[i];
        if (p >= tau) {
            int slot = atomicAdd(&s_cnt, 1);
            if (slot < FCAP) s_fp[slot] = p;
        }
    }
    __syncthreads();
    const int fcnt = s_cnt;

    if (fcnt <= FCAP) {
        // hot path: exact rank over the filtered (~35-65) packed list
        for (int e = tid; e < fcnt; e += 256) {
            u64 pe = s_fp[e];
            int rank = 0;
            for (int j = 0; j < fcnt; ++j) rank += (s_fp[j] > pe) ? 1 : 0;
            if (rank < WID) {
                s_selidx[rank] = (int)(~(unsigned)pe);
                s_selval[rank] = funkey((unsigned)(pe >> 32));
            }
        }
    } else {
        // overflow (adversarial ties): exact rank over the FULL staged 2080 list
        for (int e = tid; e < NLIST; e += 256) {
            u64 pe = s_cp[e];
            int rank = 0;
            for (int j = 0; j < NLIST; ++j) rank += (s_cp[j] > pe) ? 1 : 0;
            if (rank < WID) {
                s_selidx[rank] = (int)(~(unsigned)pe);
                s_selval[rank] = funkey((unsigned)(pe >> 32));
            }
        }
    }
    __syncthreads();

    // epilogue: per-k scalar outputs
    if (tid < WID) {
        int k = tid;
        int ind = s_selidx[k];
        bool noext = ind >= NEXT_BASE;
        int src  = noext ? (ind - NEXT_BASE) : (ind >> 11);
        int extk = ind & (VV-1);
        int plen = ylens[n*KPP + src];
        int lens = plen + (noext ? 0 : 1);
        float nbv = noext ? s_nbne[src] : s_selval[k];
        float bv  = noext ? s_bne[src]  : 0.0f;
        int lastv = noext ? s_last[src] : extk;
        size_t o = (size_t)n*WID + k;
        out[O_LAST  + o] = (float)lastv;
        out[O_LENS  + o] = (float)lens;
        out[O_NB    + o] = nbv;
        out[O_B     + o] = bv;
        out[O_SRC   + o] = (float)src;
        out[O_NOEXT + o] = noext ? 1.0f : 0.0f;
    }
}

// ---------------- kernel C: fused y_next + next_is_prefix (full-chip; round-11 proven) ----------------
__global__ void epilogue_kernel(const int* __restrict__ yprev, const int* __restrict__ pip,
                                float* __restrict__ out) {
    int id = blockIdx.x*blockDim.x + threadIdx.x;
    if (id < (int)SZ_YNEXT) {
        int k = id & 31;
        int n = (id >> 5) & 127;
        int t = id >> 12;                    // NB*WID = 4096 = 2^12
        size_t o = (size_t)n*WID + k;
        int src    = (int)out[O_SRC + o];
        bool noext = out[O_NOEXT + o] != 0.0f;
        int lens   = (int)out[O_LENS + o];
        int plen   = lens - (noext ? 0 : 1);
        int extk   = noext ? src : (int)out[O_LAST + o];
        float val;
        if (t == plen)      val = (float)extk;
        else if (t < SS)    val = (float)yprev[((size_t)t*NB + n)*KPP + src];
        else                val = 0.0f;
        out[id] = val;
    } else if (id < (int)(SZ_YNEXT + SZ_PREF)) {
        int pid = id - (int)SZ_YNEXT;
        int j = pid & 31;
        int k = (pid >> 5) & 31;
        int n = pid >> 10;
        size_t ok = (size_t)n*WID + k, oj = (size_t)n*WID + j;
        int  src_k = (int)out[O_SRC + ok];
        int  src_j = (int)out[O_SRC + oj];
        bool no_k  = out[O_NOEXT + ok] != 0.0f;
        bool no_j  = out[O_NOEXT + oj] != 0.0f;
        int  lens_k = (int)out[O_LENS + ok];
        int  lens_j = (int)out[O_LENS + oj];
        int  ext_k = no_k ? src_k : (int)out[O_LAST + ok];
        int  ext_j = no_j ? src_j : (int)out[O_LAST + oj];
        int  plen_j = lens_j - (no_j ? 0 : 1);
        bool prefix = pip[((size_t)n*KPP + src_k)*KPP + src_j] != 0;
        bool leq    = lens_k <= lens_j;
        int  tstar  = max(lens_k - 1, 0);
        int  tmj;
        if (tstar == plen_j)   tmj = ext_j;
        else if (tstar < SS)   tmj = yprev[((size_t)tstar*NB + n)*KPP + src_j];
        else                   tmj = 0;
        bool matches = (tmj == ext_k);
        bool res = prefix && leq && (no_k || matches);
        out[O_PREF + (size_t)n*WID*WID + (size_t)k*WID + j] = res ? 1.0f : 0.0f;
    }
}

extern "C" void kernel_launch(void* const* d_in, const int* in_sizes, int n_in,
                              void* d_out, int out_size, void* d_ws, size_t ws_size,
                              hipStream_t stream) {
    const float* ext    = (const float*)d_in[0];
    const float* nonext = (const float*)d_in[1];
    const float* blank  = (const float*)d_in[2];
    const float* nbp    = (const float*)d_in[3];
    const float* bp     = (const float*)d_in[4];
    const int*   yprev  = (const int*)d_in[5];
    const int*   ylast  = (const int*)d_in[6];
    const int*   ylens  = (const int*)d_in[7];
    const int*   pip    = (const int*)d_in[8];
    float* out = (float*)d_out;

    u64*   wsP  = (u64*)d_ws;                                        // NB*64*32 u64 (2 MB)
    float* wsAb = (float*)((char*)d_ws + (size_t)NB*NWAVE*WID*8);    // NB*32*32 f32 (512 KB)

    slice_topk_kernel<<<NB*KBLK, 256, 0, stream>>>(ext, nbp, bp, yprev, ylast,
                                                   ylens, pip, wsP, wsAb);
    merge_kernel<<<NB, 256, 0, stream>>>(nonext, blank, nbp, bp,
                                         ylast, ylens, wsP, wsAb, out);
    int tot = (int)(SZ_YNEXT + SZ_PREF);
    epilogue_kernel<<<(tot + 255)/256, 256, 0, stream>>>(yprev, pip, out);
}

// Round 15
// 31.324 us; speedup vs baseline: 6.0918x; 1.0225x over previous
//
#include <hip/hip_runtime.h>
#include <cstdint>
#include <cstddef>

#define NB 128      // N
#define KPP 32      // Kp
#define VV 2048     // V
#define SS 200      // S (tm1)
#define WID 32      // width == K
#define NEXT_BASE (KPP*VV)     // 65536
#define KBLK 16                // blocks per n (each block = 4 waves = 2 rows x 2 halves)
#define CAPW 128               // per-wave survivor cap
#define NWAVE (KPP*2)          // 64 wave-lists per n
#define NLIST (NWAVE*WID + WID) // 2080 merge candidates
#define FCAP 256               // merge filtered-list cap (overflow -> full exact rank)

// output layout (flat f32, concat in return order)
#define SZ_YNEXT ((size_t)(SS+1)*NB*WID)               // 823296
#define NK       ((size_t)NB*WID)                      // 4096
#define O_LAST   (SZ_YNEXT)
#define O_LENS   (SZ_YNEXT + NK)
#define O_NB     (SZ_YNEXT + 2*NK)
#define O_B      (SZ_YNEXT + 3*NK)
#define O_PREF   (SZ_YNEXT + 4*NK)                     // size NB*WID*WID
#define O_SRC    (SZ_YNEXT + 4*NK + (size_t)NB*WID*WID)
#define O_NOEXT  (SZ_YNEXT + 5*NK + (size_t)NB*WID*WID)
#define SZ_PREF  ((size_t)NB*WID*WID)                  // 131072

typedef unsigned long long u64;

__device__ __forceinline__ unsigned fkey(float f) {
    unsigned u = __float_as_uint(f);
    return (u & 0x80000000u) ? ~u : (u | 0x80000000u);
}
__device__ __forceinline__ float funkey(unsigned k) {
    unsigned u = (k & 0x80000000u) ? (k & 0x7FFFFFFFu) : ~k;
    return __uint_as_float(u);
}
__device__ __forceinline__ u64 pack(unsigned key, unsigned idx) {
    return ((u64)key << 32) | (unsigned)(~idx);        // desc value, asc idx
}
__device__ __forceinline__ u64 shflx64(u64 v, int m) {
    int lo = __shfl_xor((int)(unsigned)v, m);
    int hi = __shfl_xor((int)(unsigned)(v >> 32), m);
    return ((u64)(unsigned)hi << 32) | (unsigned)lo;
}

// ---------------- kernel A: one wave per HALF k-row, wave-autonomous ----------------
__global__ __launch_bounds__(256) void slice_topk_kernel(
    const float* __restrict__ ext,     // [N][Kp][V]
    const float* __restrict__ nbp_g,   // [N][Kp]
    const float* __restrict__ bp_g,    // [N][Kp]
    const int*   __restrict__ yprev,   // [S][N][Kp]
    const int*   __restrict__ ylast,   // [N][Kp]
    const int*   __restrict__ ylens,   // [N][Kp]
    const int*   __restrict__ pip,     // [N][Kp][Kp]
    u64* __restrict__ wsP, float* __restrict__ wsAb)
{
    const int blk  = blockIdx.x;
    const int n    = blk >> 4;          // KBLK = 16
    const int kb   = blk & 15;
    const int tid  = threadIdx.x;
    const int w    = tid >> 6;          // 4 waves
    const int lane = tid & 63;
    const int k    = kb*2 + (w >> 1);
    const int half = w & 1;
    const int g    = ((n*KPP + k) << 1) + half;   // this wave's ws list id

    __shared__ unsigned s_hm[4][VV/32];                       // wave-private hm, 1 KB
    __shared__ u64 __attribute__((aligned(16))) s_bp64[4][CAPW];  // packed survivors, 4 KB

    s_hm[w][lane] = 0u;                 // VV/32 == 64 == lane count (wave-private)

    // per-row params (wave-uniform addresses -> broadcast loads)
    const int   tlen = ylens[n*KPP + k];
    int last = ylast[n*KPP + k]; last = min(max(last, 0), VV-1);
    const float nbp = nbp_g[n*KPP + k];
    const float bp  = bp_g[n*KPP + k];

    // issue the 4 float4 loads early (16 floats/lane, registers only)
    const float4* g4 = (const float4*)(ext + ((size_t)n*KPP + k)*VV + half*1024);
    float4 f[4];
    #pragma unroll
    for (int j = 0; j < 4; ++j) f[j] = g4[lane + 64*j];

    // has-match bits + absorb terms (same-wave LDS ordering; no barrier needed)
    if (lane < KPP) {
        int j = lane;
        int tcl = min(max(tlen, 0), SS-1);
        int tm  = yprev[((size_t)tcl*NB + n)*KPP + j];
        tm = min(max(tm, 0), VV-1);
        bool ex = (tlen + 1 == ylens[n*KPP + j]) && (pip[((size_t)n*KPP + k)*KPP + j] != 0);
        if (ex) atomicOr(&s_hm[w][tm >> 5], 1u << (tm & 31));
        if (half == 0) {
            float ev = ex ? ext[((size_t)n*KPP + k)*VV + tm] : 0.0f;
            float bb = (tm == last) ? 0.0f : nbp;
            wsAb[((size_t)n*KPP + k)*KPP + j] = ex ? (bb + bp)*ev : 0.0f;
        }
    }

    // hm preload: key i = 4j+e touches word (half<<5) + 8j + (lane>>3), independent of e
    unsigned hmw[4];
    #pragma unroll
    for (int j = 0; j < 4; ++j) hmw[j] = s_hm[w][(half << 5) + 8*j + (lane >> 3)];
    const int bsh = (lane & 7) << 2;    // bit index base: ((lane&7)<<2) + e

    // 16 keys in registers; v_local = 4*lane + 256*j + e in [0,1024)
    unsigned key[16];
    #pragma unroll
    for (int j = 0; j < 4; ++j) {
        const float fe[4] = {f[j].x, f[j].y, f[j].z, f[j].w};
        #pragma unroll
        for (int e = 0; e < 4; ++e) {
            int vl = 4*lane + 256*j + e;
            int v  = (half << 10) + vl;
            float base = (v == last) ? 0.0f : nbp;
            float val  = (base + bp) * fe[e];
            if ((hmw[j] >> (bsh + e)) & 1u) val = -INFINITY;
            key[j*4 + e] = fkey(val);
        }
    }

    // lane max (top 16 bits suffice for the threshold)
    unsigned m = key[0];
    #pragma unroll
    for (int i = 1; i < 16; ++i) m = max(m, key[i]);
    const unsigned m16 = m >> 16;

    // tau16 = EXACT 32nd-largest of the 64 (lane-max >> 16) values: 16 ballot steps
    unsigned tau16 = 0;
    {
        int need = 32;
        #pragma unroll
        for (int b = 15; b >= 0; --b) {
            unsigned pb1 = (tau16 >> b) | 1u;
            unsigned long long msk = __ballot((m16 >> b) == pb1);
            int cnt = __popcll(msk);
            if (cnt >= need) tau16 |= (1u << b);
            else             need -= cnt;
        }
    }
    // guarantee: >=32 lanes have (m>>16) >= tau16  =>  >=32 keys with (key>>16) >= tau16

    // optimistic gather into wave-private LDS (packed); count via ballot prefix
    const unsigned long long lmask = (1ull << lane) - 1ull;
    int off2 = 0;
    #pragma unroll
    for (int i = 0; i < 16; ++i) {
        bool sel = (key[i] >> 16) >= tau16;
        unsigned long long msk = __ballot(sel);
        if (sel) {
            int slot = off2 + __popcll(msk & lmask);
            if (slot < CAPW) {
                unsigned gidx = (unsigned)((k << 11) + (half << 10) + (4*lane + 256*(i >> 2) + (i & 3)));
                s_bp64[w][slot] = pack(key[i], gidx);
            }
        }
        off2 += __popcll(msk);
    }
    int total = off2;

    if (total > CAPW) {
        // exact fallback: key-bit radix, then idx radix among ties (shuffle-only)
        int need = WID;
        unsigned T = 0, istar = 0;
        for (int b = 31; b >= 0; --b) {
            unsigned pb1 = (T >> b) | 1u;
            int c1 = 0;
            #pragma unroll
            for (int i = 0; i < 16; ++i) c1 += ((key[i] >> b) == pb1) ? 1 : 0;
            #pragma unroll
            for (int off = 32; off; off >>= 1) c1 += __shfl_xor(c1, off);
            if (c1 >= need) T |= (1u << b);
            else need -= c1;
        }
        for (int b = 9; b >= 0; --b) {          // v_local < 1024 -> 10 bits
            int c0 = 0;
            #pragma unroll
            for (int i = 0; i < 16; ++i) {
                unsigned vv = (unsigned)(4*lane + 256*(i >> 2) + (i & 3));
                if (key[i] == T && (vv >> (b+1)) == (istar >> (b+1)) && !((vv >> b) & 1u)) c0++;
            }
            #pragma unroll
            for (int off = 32; off; off >>= 1) c0 += __shfl_xor(c0, off);
            if (c0 >= need) { } else { need -= c0; istar |= (1u << b); }
        }
        int o2 = 0;
        #pragma unroll
        for (int i = 0; i < 16; ++i) {
            unsigned vv = (unsigned)(4*lane + 256*(i >> 2) + (i & 3));
            bool sel = (key[i] > T || (key[i] == T && vv <= istar));
            unsigned long long msk = __ballot(sel);
            if (sel) {
                int slot = o2 + __popcll(msk & lmask);
                unsigned gidx = (unsigned)((k << 11) + (half << 10) + (int)vv);
                s_bp64[w][slot] = pack(key[i], gidx);
            }
            o2 += __popcll(msk);
        }
        total = WID;    // exactly 32 selected
    }

    // in-wave rank-sort (~44 elements); paired b128 reads; top-32 packed to ws
    {
        const ulonglong2* pb2 = (const ulonglong2*)(&s_bp64[w][0]);
        const int nt2 = total >> 1;
        for (int e = lane; e < total; e += 64) {
            u64 pe = s_bp64[w][e];
            int rank = 0;
            for (int q = 0; q < nt2; ++q) {
                ulonglong2 t2 = pb2[q];
                rank += (t2.x > pe) ? 1 : 0;
                rank += (t2.y > pe) ? 1 : 0;
            }
            if (total & 1) rank += (s_bp64[w][total-1] > pe) ? 1 : 0;
            if (rank < WID) wsP[(size_t)g*WID + rank] = pe;
        }
    }
}

// ---------------- kernel B: merge (packed tau-filter) + epilogue scalars ----------------
__global__ __launch_bounds__(256) void merge_kernel(
    const float* __restrict__ nonext,
    const float* __restrict__ blank,
    const float* __restrict__ nbp_g,
    const float* __restrict__ bp_g,
    const int*   __restrict__ ylast,
    const int*   __restrict__ ylens,
    const u64* __restrict__ wsP, const float* __restrict__ wsAb,
    float* __restrict__ out)
{
    const int n   = blockIdx.x;
    const int tid = threadIdx.x;

    __shared__ int      s_last[KPP];
    __shared__ float    s_bne[KPP], s_nbne[KPP];
    __shared__ float    s_abL[KPP][KPP];
    __shared__ u64      s_cp[NLIST];                              // packed, 16.6 KB
    __shared__ u64 __attribute__((aligned(16))) s_fp[FCAP];
    __shared__ u64      s_tau;
    __shared__ int      s_cnt;
    __shared__ int      s_selidx[WID];
    __shared__ float    s_selval[WID];

    if (tid == 0) s_cnt = 0;
    if (tid < KPP) {
        int k = tid;
        int last = ylast[n*KPP + k]; last = min(max(last, 0), VV-1);
        float a = nbp_g[n*KPP + k], b = bp_g[n*KPP + k];
        s_last[k] = last;
        s_bne[k]  = (a + b) * blank[n];
        s_nbne[k] = a * nonext[(size_t)n*VV + last];
    }
    for (int i = tid; i < KPP*KPP; i += 256)
        s_abL[i >> 5][i & 31] = wsAb[(size_t)n*KPP*KPP + i];
    __syncthreads();
    if (tid < KPP) {    // absorb: serial k-order sum (bit-exact; zero terms neutral)
        int j = tid;
        float acc = s_nbne[j];
        #pragma unroll
        for (int k = 0; k < KPP; ++k) acc += s_abL[k][j];
        s_nbne[j] = acc;
    }
    __syncthreads();

    // candidate list: 64 wave-top-32s (packed, coalesced 8B loads) + 32 nonext
    for (int i = tid; i < NLIST; i += 256) {
        if (i < NWAVE*WID) {
            s_cp[i] = wsP[(size_t)n*NWAVE*WID + i];
        } else {
            int j = i - NWAVE*WID;
            s_cp[i] = pack(fkey(s_nbne[j] + s_bne[j]), (unsigned)(NEXT_BASE + j));
        }
    }
    __syncthreads();

    // tau = max over waves of their 32nd packed key (lower bound on global 32nd)
    if (tid < 64) {
        u64 p = s_cp[tid*WID + (WID-1)];
        #pragma unroll
        for (int off = 32; off; off >>= 1) {
            u64 o = shflx64(p, off);
            if (o > p) p = o;
        }
        if (tid == 0) s_tau = p;
    }
    __syncthreads();
    const u64 tau = s_tau;

    for (int i = tid; i < NLIST; i += 256) {
        u64 p = s_cp[i];
        if (p >= tau) {
            int slot = atomicAdd(&s_cnt, 1);
            if (slot < FCAP) s_fp[slot] = p;
        }
    }
    __syncthreads();
    const int fcnt = s_cnt;

    if (fcnt <= FCAP) {
        // hot path: exact rank over the filtered (~35-65) packed list, paired reads
        const ulonglong2* pf2 = (const ulonglong2*)(&s_fp[0]);
        const int nf2 = fcnt >> 1;
        for (int e = tid; e < fcnt; e += 256) {
            u64 pe = s_fp[e];
            int rank = 0;
            for (int q = 0; q < nf2; ++q) {
                ulonglong2 t2 = pf2[q];
                rank += (t2.x > pe) ? 1 : 0;
                rank += (t2.y > pe) ? 1 : 0;
            }
            if (fcnt & 1) rank += (s_fp[fcnt-1] > pe) ? 1 : 0;
            if (rank < WID) {
                s_selidx[rank] = (int)(~(unsigned)pe);
                s_selval[rank] = funkey((unsigned)(pe >> 32));
            }
        }
    } else {
        // overflow (adversarial ties): exact rank over the FULL staged 2080 list
        for (int e = tid; e < NLIST; e += 256) {
            u64 pe = s_cp[e];
            int rank = 0;
            for (int j = 0; j < NLIST; ++j) rank += (s_cp[j] > pe) ? 1 : 0;
            if (rank < WID) {
                s_selidx[rank] = (int)(~(unsigned)pe);
                s_selval[rank] = funkey((unsigned)(pe >> 32));
            }
        }
    }
    __syncthreads();

    // epilogue: per-k scalar outputs
    if (tid < WID) {
        int k = tid;
        int ind = s_selidx[k];
        bool noext = ind >= NEXT_BASE;
        int src  = noext ? (ind - NEXT_BASE) : (ind >> 11);
        int extk = ind & (VV-1);
        int plen = ylens[n*KPP + src];
        int lens = plen + (noext ? 0 : 1);
        float nbv = noext ? s_nbne[src] : s_selval[k];
        float bv  = noext ? s_bne[src]  : 0.0f;
        int lastv = noext ? s_last[src] : extk;
        size_t o = (size_t)n*WID + k;
        out[O_LAST  + o] = (float)lastv;
        out[O_LENS  + o] = (float)lens;
        out[O_NB    + o] = nbv;
        out[O_B     + o] = bv;
        out[O_SRC   + o] = (float)src;
        out[O_NOEXT + o] = noext ? 1.0f : 0.0f;
    }
}

// ---------------- kernel C: fused y_next + next_is_prefix (full-chip) ----------------
__global__ void epilogue_kernel(const int* __restrict__ yprev, const int* __restrict__ pip,
                                float* __restrict__ out) {
    int id = blockIdx.x*blockDim.x + threadIdx.x;
    if (id < (int)SZ_YNEXT) {
        int k = id & 31;
        int n = (id >> 5) & 127;
        int t = id >> 12;                    // NB*WID = 4096 = 2^12
        size_t o = (size_t)n*WID + k;
        int src    = (int)out[O_SRC + o];
        bool noext = out[O_NOEXT + o] != 0.0f;
        int lens   = (int)out[O_LENS + o];
        int plen   = lens - (noext ? 0 : 1);
        int extk   = noext ? src : (int)out[O_LAST + o];
        float val;
        if (t == plen)      val = (float)extk;
        else if (t < SS)    val = (float)yprev[((size_t)t*NB + n)*KPP + src];
        else                val = 0.0f;
        out[id] = val;
    } else if (id < (int)(SZ_YNEXT + SZ_PREF)) {
        int pid = id - (int)SZ_YNEXT;
        int j = pid & 31;
        int k = (pid >> 5) & 31;
        int n = pid >> 10;
        size_t ok = (size_t)n*WID + k, oj = (size_t)n*WID + j;
        int  src_k = (int)out[O_SRC + ok];
        int  src_j = (int)out[O_SRC + oj];
        bool no_k  = out[O_NOEXT + ok] != 0.0f;
        bool no_j  = out[O_NOEXT + oj] != 0.0f;
        int  lens_k = (int)out[O_LENS + ok];
        int  lens_j = (int)out[O_LENS + oj];
        int  ext_k = no_k ? src_k : (int)out[O_LAST + ok];
        int  ext_j = no_j ? src_j : (int)out[O_LAST + oj];
        int  plen_j = lens_j - (no_j ? 0 : 1);
        bool prefix = pip[((size_t)n*KPP + src_k)*KPP + src_j] != 0;
        bool leq    = lens_k <= lens_j;
        int  tstar  = max(lens_k - 1, 0);
        int  tmj;
        if (tstar == plen_j)   tmj = ext_j;
        else if (tstar < SS)   tmj = yprev[((size_t)tstar*NB + n)*KPP + src_j];
        else                   tmj = 0;
        bool matches = (tmj == ext_k);
        bool res = prefix && leq && (no_k || matches);
        out[O_PREF + (size_t)n*WID*WID + (size_t)k*WID + j] = res ? 1.0f : 0.0f;
    }
}

extern "C" void kernel_launch(void* const* d_in, const int* in_sizes, int n_in,
                              void* d_out, int out_size, void* d_ws, size_t ws_size,
                              hipStream_t stream) {
    const float* ext    = (const float*)d_in[0];
    const float* nonext = (const float*)d_in[1];
    const float* blank  = (const float*)d_in[2];
    const float* nbp    = (const float*)d_in[3];
    const float* bp     = (const float*)d_in[4];
    const int*   yprev  = (const int*)d_in[5];
    const int*   ylast  = (const int*)d_in[6];
    const int*   ylens  = (const int*)d_in[7];
    const int*   pip    = (const int*)d_in[8];
    float* out = (float*)d_out;

    u64*   wsP  = (u64*)d_ws;                                        // NB*64*32 u64 (2 MB)
    float* wsAb = (float*)((char*)d_ws + (size_t)NB*NWAVE*WID*8);    // NB*32*32 f32 (512 KB)

    slice_topk_kernel<<<NB*KBLK, 256, 0, stream>>>(ext, nbp, bp, yprev, ylast,
                                                   ylens, pip, wsP, wsAb);
    merge_kernel<<<NB, 256, 0, stream>>>(nonext, blank, nbp, bp,
                                         ylast, ylens, wsP, wsAb, out);
    int tot = (int)(SZ_YNEXT + SZ_PREF);
    epilogue_kernel<<<(tot + 255)/256, 256, 0, stream>>>(yprev, pip, out);
}